// Round 1
// baseline (16438.245 us; speedup 1.0000x reference)
//
#include <hip/hip_runtime.h>
#include <math.h>

#define NDIM 4096
#define DDIM 1024
#define TSTEPS 1024
#define NWG 128
#define COLSPW 32   // NDIM / NWG

// ---------------- global min/max of attn over all B*N ----------------
__global__ __launch_bounds__(256) void k_minmax(const float* __restrict__ attn, int n,
                                                float* __restrict__ mm) {
  __shared__ float smin[4], smax[4];
  float vmin = INFINITY, vmax = -INFINITY;
  for (int i = threadIdx.x; i < n; i += 256) {
    float a = attn[i];
    vmin = fminf(vmin, a);
    vmax = fmaxf(vmax, a);
  }
#pragma unroll
  for (int m = 32; m >= 1; m >>= 1) {
    vmin = fminf(vmin, __shfl_xor(vmin, m, 64));
    vmax = fmaxf(vmax, __shfl_xor(vmax, m, 64));
  }
  if ((threadIdx.x & 63) == 0) { smin[threadIdx.x >> 6] = vmin; smax[threadIdx.x >> 6] = vmax; }
  __syncthreads();
  if (threadIdx.x == 0) {
    mm[0] = fminf(fminf(smin[0], smin[1]), fminf(smin[2], smin[3]));
    mm[1] = fmaxf(fmaxf(smax[0], smax[1]), fmaxf(smax[2], smax[3]));
  }
}

// ---------------- per-row normalize (batch 0) + rnorm ----------------
__global__ __launch_bounds__(256) void k_prep(const float* __restrict__ X,
                                              const float* __restrict__ attn,
                                              const float* __restrict__ mm,
                                              float* __restrict__ Xn,
                                              float* __restrict__ rnorm) {
  __shared__ float sp[4];
  __shared__ float s_norm;
  const int tid = threadIdx.x;
  const int row = blockIdx.x;
  const float* xr = X + (size_t)row * DDIM;
  float4 v = *(const float4*)(xr + tid * 4);
  float ss = v.x * v.x + v.y * v.y + v.z * v.z + v.w * v.w;
#pragma unroll
  for (int m = 32; m >= 1; m >>= 1) ss += __shfl_xor(ss, m, 64);
  if ((tid & 63) == 0) sp[tid >> 6] = ss;
  __syncthreads();
  if (tid == 0) {
    float tot = (sp[0] + sp[1]) + (sp[2] + sp[3]);
    s_norm = sqrtf(tot);
    float amin = mm[0], amax = mm[1];
    float t1 = amax - attn[row];           // == (-a) - rmin
    rnorm[row] = (t1 + 1e-6f) / (amax - amin);
  }
  __syncthreads();
  float nrm = s_norm;
  float4 o;
  o.x = v.x / nrm; o.y = v.y / nrm; o.z = v.z / nrm; o.w = v.w / nrm;
  *(float4*)(Xn + (size_t)row * DDIM + tid * 4) = o;
}

// ---------------- S = Xn * Xn^T  (f32, vector ALU) ----------------
// 64x64 tile per block, BK=16, k-major LDS so fragment reads are ds_read_b128.
__global__ __launch_bounds__(256) void k_gemm(const float* __restrict__ Xn,
                                              float* __restrict__ S) {
  __shared__ float As[16][68];
  __shared__ float Bs[16][68];
  const int tid = threadIdx.x;
  const int by = blockIdx.x >> 6, bx = blockIdx.x & 63;
  const int i0 = by << 6, j0 = bx << 6;
  const int tx = tid & 15, ty = tid >> 4;
  const int lr = tid >> 2, lk = (tid & 3) << 2;
  float acc[4][4] = {};
  const float* Ap = Xn + (size_t)(i0 + lr) * DDIM + lk;
  const float* Bp = Xn + (size_t)(j0 + lr) * DDIM + lk;
  for (int k0 = 0; k0 < DDIM; k0 += 16) {
    float4 av = *(const float4*)(Ap + k0);
    float4 bv = *(const float4*)(Bp + k0);
    __syncthreads();  // WAR guard vs previous iteration's reads
    As[lk + 0][lr] = av.x; As[lk + 1][lr] = av.y; As[lk + 2][lr] = av.z; As[lk + 3][lr] = av.w;
    Bs[lk + 0][lr] = bv.x; Bs[lk + 1][lr] = bv.y; Bs[lk + 2][lr] = bv.z; Bs[lk + 3][lr] = bv.w;
    __syncthreads();
#pragma unroll
    for (int k = 0; k < 16; ++k) {
      float4 a = *(const float4*)&As[k][ty << 2];
      float4 b = *(const float4*)&Bs[k][tx << 2];
      acc[0][0] = fmaf(a.x, b.x, acc[0][0]); acc[0][1] = fmaf(a.x, b.y, acc[0][1]);
      acc[0][2] = fmaf(a.x, b.z, acc[0][2]); acc[0][3] = fmaf(a.x, b.w, acc[0][3]);
      acc[1][0] = fmaf(a.y, b.x, acc[1][0]); acc[1][1] = fmaf(a.y, b.y, acc[1][1]);
      acc[1][2] = fmaf(a.y, b.z, acc[1][2]); acc[1][3] = fmaf(a.y, b.w, acc[1][3]);
      acc[2][0] = fmaf(a.z, b.x, acc[2][0]); acc[2][1] = fmaf(a.z, b.y, acc[2][1]);
      acc[2][2] = fmaf(a.z, b.z, acc[2][2]); acc[2][3] = fmaf(a.z, b.w, acc[2][3]);
      acc[3][0] = fmaf(a.w, b.x, acc[3][0]); acc[3][1] = fmaf(a.w, b.y, acc[3][1]);
      acc[3][2] = fmaf(a.w, b.z, acc[3][2]); acc[3][3] = fmaf(a.w, b.w, acc[3][3]);
    }
  }
#pragma unroll
  for (int m = 0; m < 4; ++m) {
    float4 o;
    o.x = acc[m][0]; o.y = acc[m][1]; o.z = acc[m][2]; o.w = acc[m][3];
    *(float4*)(S + (size_t)(i0 + (ty << 2) + m) * NDIM + j0 + (tx << 2)) = o;
  }
}

// ---------------- persistent greedy-DPP scan ----------------
__device__ __forceinline__ void vimerge(float& v, int& id, float v2, int id2) {
  if (v2 > v || (v2 == v && id2 < id)) { v = v2; id = id2; }
}

__device__ __forceinline__ void gbar(unsigned* cnt, unsigned target) {
  __syncthreads();
  if (threadIdx.x == 0) {
    __threadfence();  // release: make this WG's writes agent-visible
    __hip_atomic_fetch_add(cnt, 1u, __ATOMIC_ACQ_REL, __HIP_MEMORY_SCOPE_AGENT);
    while (__hip_atomic_load(cnt, __ATOMIC_ACQUIRE, __HIP_MEMORY_SCOPE_AGENT) < target) {
      __builtin_amdgcn_s_sleep(4);
    }
    __threadfence();  // acquire: invalidate stale cached lines
  }
  __syncthreads();
}

__global__ __launch_bounds__(256) void k_scan(const float* __restrict__ S,
                                              const float* __restrict__ rnorm,
                                              float* __restrict__ cisT,   // [N][T]
                                              float* __restrict__ pvals,  // [2][NWG]
                                              int* __restrict__ pidx,     // [2][NWG]
                                              unsigned* __restrict__ barcnt,
                                              int* __restrict__ sel) {
  __shared__ float cjL[TSTEPS];
  __shared__ float di2sL[COLSPW];
  __shared__ float rnL[COLSPW];
  __shared__ float pvL[NWG];
  __shared__ int piL[NWG];
  __shared__ float s_dj;
  __shared__ int s_j;

  const int tid = threadIdx.x;
  const int wg = blockIdx.x;
  const int col = tid >> 3;   // 0..31
  const int lane8 = tid & 7;  // 8 lanes per column
  const int n = wg * COLSPW + col;
  unsigned barnum = 0;

  // ---- init: di2s = (r_n * S_nn) * r_n, partial argmax into buffer 0 ----
  if (tid < COLSPW) {
    int nn = wg * COLSPW + tid;
    float rn = rnorm[nn];
    rnL[tid] = rn;
    float diag = S[(size_t)nn * NDIM + nn];
    di2sL[tid] = (rn * diag) * rn;
  }
  __syncthreads();
  if (tid < 32) {
    float v = di2sL[tid]; int id = wg * COLSPW + tid;
#pragma unroll
    for (int m = 16; m >= 1; m >>= 1)
      vimerge(v, id, __shfl_xor(v, m, 64), __shfl_xor(id, m, 64));
    if (tid == 0) { pvals[wg] = v; pidx[wg] = id; }
  }
  barnum++;
  gbar(barcnt, barnum * NWG);

  const float4* crow = (const float4*)(cisT + (size_t)n * TSTEPS);

  for (int i = 0; i < TSTEPS; ++i) {
    const int rb = (i & 1) * NWG;        // read buffer
    const int wb = ((i + 1) & 1) * NWG;  // write buffer (for step i+1)

    // ---- global argmax over the 128 partials (every WG redundantly) ----
    if (tid < NWG) { pvL[tid] = pvals[rb + tid]; piL[tid] = pidx[rb + tid]; }
    __syncthreads();
    if (tid < 64) {
      float v = pvL[tid]; int id = piL[tid];
      vimerge(v, id, pvL[tid + 64], piL[tid + 64]);
#pragma unroll
      for (int m = 32; m >= 1; m >>= 1)
        vimerge(v, id, __shfl_xor(v, m, 64), __shfl_xor(id, m, 64));
      if (tid == 0) { s_j = id; s_dj = v; }
    }
    __syncthreads();
    const int j = s_j;
    const float dj = s_dj;
    if (wg == 0 && tid == 0) sel[i] = j;

    // ---- stage cj = cisT[j, 0:i] into LDS ----
    const float* cjrow = cisT + (size_t)j * TSTEPS;
    {
      int t4 = tid << 2;
      if (t4 < i) *(float4*)(cjL + t4) = *(const float4*)(cjrow + t4);
    }
    __syncthreads();

    // ---- contraction s = sum_{t<i} cj[t] * cis[t, n] for own columns ----
    float s = 0.f;
    const int nq = i >> 2;
    for (int q = lane8; q < nq; q += 8) {
      float4 c = crow[q];
      float4 cj = *(const float4*)(cjL + (q << 2));
      s = fmaf(c.x, cj.x, s); s = fmaf(c.y, cj.y, s);
      s = fmaf(c.z, cj.z, s); s = fmaf(c.w, cj.w, s);
    }
    s += __shfl_xor(s, 4, 64);
    s += __shfl_xor(s, 2, 64);
    s += __shfl_xor(s, 1, 64);
    if (lane8 == 0) {
      for (int t = nq << 2; t < i; ++t)
        s = fmaf(cisT[(size_t)n * TSTEPS + t], cjL[t], s);
      float kjn = (rnorm[j] * S[(size_t)j * NDIM + n]) * rnL[col];
      float eis = (kjn - s) / sqrtf(dj);
      float d = __fsub_rn(di2sL[col], __fmul_rn(eis, eis));
      if (n == j) d = -INFINITY;
      di2sL[col] = d;
      cisT[(size_t)n * TSTEPS + i] = eis;
    }
    __syncthreads();

    // ---- partial argmax for next step into the other buffer ----
    if (tid < 32) {
      float v = di2sL[tid]; int id = wg * COLSPW + tid;
#pragma unroll
      for (int m = 16; m >= 1; m >>= 1)
        vimerge(v, id, __shfl_xor(v, m, 64), __shfl_xor(id, m, 64));
      if (tid == 0) { pvals[wb + wg] = v; pidx[wb + wg] = id; }
    }
    barnum++;
    gbar(barcnt, barnum * NWG);
  }
}

extern "C" void kernel_launch(void* const* d_in, const int* in_sizes, int n_in,
                              void* d_out, int out_size, void* d_ws, size_t ws_size,
                              hipStream_t stream) {
  const float* X = (const float*)d_in[0];      // [2,4096,1024] f32
  const float* attn = (const float*)d_in[1];   // [2,4096] f32
  int* sel = (int*)d_out;                      // [1024] int32
  char* ws = (char*)d_ws;

  float* mm = (float*)ws;                          // 2 f
  float* rnorm = (float*)(ws + 4096);              // 4096 f (16 KB)
  float* pvals = (float*)(ws + 20480);             // 2*128 f
  int* pidx = (int*)(ws + 21504);                  // 2*128 i
  unsigned* barcnt = (unsigned*)(ws + 24576);      // 1 u32
  char* big = ws + 65536;
  float* Xn = (float*)big;                                  // 16 MB
  float* S = (float*)(big + (size_t)16 * 1024 * 1024);      // 64 MB
  float* cisT = (float*)(big + (size_t)80 * 1024 * 1024);   // 16 MB

  const int nattn = in_sizes[1];  // 8192

  hipMemsetAsync(barcnt, 0, 64, stream);
  k_minmax<<<1, 256, 0, stream>>>(attn, nattn, mm);
  k_prep<<<NDIM, 256, 0, stream>>>(X, attn, mm, Xn, rnorm);
  k_gemm<<<64 * 64, 256, 0, stream>>>(Xn, S);
  k_scan<<<NWG, 256, 0, stream>>>(S, rnorm, cisT, pvals, pidx, barcnt, sel);
}

// Round 5
// 8275.762 us; speedup vs baseline: 1.9863x; 1.9863x over previous
//
#include <hip/hip_runtime.h>
#include <math.h>

#define NDIM 4096
#define DDIM 1024
#define TSTEPS 1024
#define NWG 64
#define NTHR 1024
#define COLSPW 64   // NDIM / NWG
// 16 lanes per column, 64 columns per WG

// ---------------- global min/max of attn over all B*N ----------------
__global__ __launch_bounds__(256) void k_minmax(const float* __restrict__ attn, int n,
                                                float* __restrict__ mm) {
  __shared__ float smin[4], smax[4];
  float vmin = INFINITY, vmax = -INFINITY;
  for (int i = threadIdx.x; i < n; i += 256) {
    float a = attn[i];
    vmin = fminf(vmin, a);
    vmax = fmaxf(vmax, a);
  }
#pragma unroll
  for (int m = 32; m >= 1; m >>= 1) {
    vmin = fminf(vmin, __shfl_xor(vmin, m, 64));
    vmax = fmaxf(vmax, __shfl_xor(vmax, m, 64));
  }
  if ((threadIdx.x & 63) == 0) { smin[threadIdx.x >> 6] = vmin; smax[threadIdx.x >> 6] = vmax; }
  __syncthreads();
  if (threadIdx.x == 0) {
    mm[0] = fminf(fminf(smin[0], smin[1]), fminf(smin[2], smin[3]));
    mm[1] = fmaxf(fmaxf(smax[0], smax[1]), fmaxf(smax[2], smax[3]));
  }
}

// ---------------- per-row normalize (batch 0) + rnorm ----------------
__global__ __launch_bounds__(256) void k_prep(const float* __restrict__ X,
                                              const float* __restrict__ attn,
                                              const float* __restrict__ mm,
                                              float* __restrict__ Xn,
                                              float* __restrict__ rnorm) {
  __shared__ float sp[4];
  __shared__ float s_norm;
  const int tid = threadIdx.x;
  const int row = blockIdx.x;
  const float* xr = X + (size_t)row * DDIM;
  float4 v = *(const float4*)(xr + tid * 4);
  float ss = v.x * v.x + v.y * v.y + v.z * v.z + v.w * v.w;
#pragma unroll
  for (int m = 32; m >= 1; m >>= 1) ss += __shfl_xor(ss, m, 64);
  if ((tid & 63) == 0) sp[tid >> 6] = ss;
  __syncthreads();
  if (tid == 0) {
    float tot = (sp[0] + sp[1]) + (sp[2] + sp[3]);
    s_norm = sqrtf(tot);
    float amin = mm[0], amax = mm[1];
    float t1 = amax - attn[row];           // == (-a) - rmin
    rnorm[row] = (t1 + 1e-6f) / (amax - amin);
  }
  __syncthreads();
  float nrm = s_norm;
  float4 o;
  o.x = v.x / nrm; o.y = v.y / nrm; o.z = v.z / nrm; o.w = v.w / nrm;
  *(float4*)(Xn + (size_t)row * DDIM + tid * 4) = o;
}

// ---------------- S = Xn * Xn^T  (f32, vector ALU) ----------------
__global__ __launch_bounds__(256) void k_gemm(const float* __restrict__ Xn,
                                              float* __restrict__ S) {
  __shared__ float As[16][68];
  __shared__ float Bs[16][68];
  const int tid = threadIdx.x;
  const int by = blockIdx.x >> 6, bx = blockIdx.x & 63;
  const int i0 = by << 6, j0 = bx << 6;
  const int tx = tid & 15, ty = tid >> 4;
  const int lr = tid >> 2, lk = (tid & 3) << 2;
  float acc[4][4] = {};
  const float* Ap = Xn + (size_t)(i0 + lr) * DDIM + lk;
  const float* Bp = Xn + (size_t)(j0 + lr) * DDIM + lk;
  for (int k0 = 0; k0 < DDIM; k0 += 16) {
    float4 av = *(const float4*)(Ap + k0);
    float4 bv = *(const float4*)(Bp + k0);
    __syncthreads();
    As[lk + 0][lr] = av.x; As[lk + 1][lr] = av.y; As[lk + 2][lr] = av.z; As[lk + 3][lr] = av.w;
    Bs[lk + 0][lr] = bv.x; Bs[lk + 1][lr] = bv.y; Bs[lk + 2][lr] = bv.z; Bs[lk + 3][lr] = bv.w;
    __syncthreads();
#pragma unroll
    for (int k = 0; k < 16; ++k) {
      float4 a = *(const float4*)&As[k][ty << 2];
      float4 b = *(const float4*)&Bs[k][tx << 2];
      acc[0][0] = fmaf(a.x, b.x, acc[0][0]); acc[0][1] = fmaf(a.x, b.y, acc[0][1]);
      acc[0][2] = fmaf(a.x, b.z, acc[0][2]); acc[0][3] = fmaf(a.x, b.w, acc[0][3]);
      acc[1][0] = fmaf(a.y, b.x, acc[1][0]); acc[1][1] = fmaf(a.y, b.y, acc[1][1]);
      acc[1][2] = fmaf(a.y, b.z, acc[1][2]); acc[1][3] = fmaf(a.y, b.w, acc[1][3]);
      acc[2][0] = fmaf(a.z, b.x, acc[2][0]); acc[2][1] = fmaf(a.z, b.y, acc[2][1]);
      acc[2][2] = fmaf(a.z, b.z, acc[2][2]); acc[2][3] = fmaf(a.z, b.w, acc[2][3]);
      acc[3][0] = fmaf(a.w, b.x, acc[3][0]); acc[3][1] = fmaf(a.w, b.y, acc[3][1]);
      acc[3][2] = fmaf(a.w, b.z, acc[3][2]); acc[3][3] = fmaf(a.w, b.w, acc[3][3]);
    }
  }
#pragma unroll
  for (int m = 0; m < 4; ++m) {
    float4 o;
    o.x = acc[m][0]; o.y = acc[m][1]; o.z = acc[m][2]; o.w = acc[m][3];
    *(float4*)(S + (size_t)(i0 + (ty << 2) + m) * NDIM + j0 + (tx << 2)) = o;
  }
}

// ---------------- persistent greedy-DPP scan ----------------
__device__ __forceinline__ void vimerge(float& v, int& id, float v2, int id2) {
  if (v2 > v || (v2 == v && id2 < id)) { v = v2; id = id2; }
}

// monotone float->u32 encoding; low field prefers smaller index on ties
__device__ __forceinline__ unsigned long long packvi(float v, int idx) {
  unsigned u = __float_as_uint(v);
  u = (u & 0x80000000u) ? ~u : (u | 0x80000000u);
  return ((unsigned long long)u << 32) | (unsigned)(NDIM - 1 - idx);
}

__device__ __forceinline__ void gbar(unsigned* cnt, unsigned target) {
  __syncthreads();
  if (threadIdx.x == 0) {
    __threadfence();  // release this WG's writes to agent scope
    __hip_atomic_fetch_add(cnt, 1u, __ATOMIC_RELEASE, __HIP_MEMORY_SCOPE_AGENT);
    while (__hip_atomic_load(cnt, __ATOMIC_RELAXED, __HIP_MEMORY_SCOPE_AGENT) < target)
      __builtin_amdgcn_s_sleep(2);  // all 64 WGs co-resident -> terminates
    __threadfence();  // acquire: invalidate stale cached lines
  }
  __syncthreads();
}

__global__ __launch_bounds__(NTHR) void k_scan(const float* __restrict__ S,
                                               const float* __restrict__ rnorm,
                                               float* __restrict__ cisT,  // [N][T], pre-zeroed
                                               unsigned long long* __restrict__ gmax,
                                               unsigned* __restrict__ barcnt,
                                               int* __restrict__ sel) {
  __shared__ float di2sL[COLSPW];
  __shared__ float rnL[COLSPW];

  const int tid = threadIdx.x;
  const int wg = blockIdx.x;
  const int col = tid >> 4;   // 0..63
  const int lane = tid & 15;  // 16 lanes per column
  const int n = wg * COLSPW + col;
  const float4* crow = (const float4*)(cisT + (size_t)n * TSTEPS);

  // ---- init: di2s = (r_n * S_nn) * r_n; partial argmax -> gmax[0] ----
  if (tid < COLSPW) {
    int nn = wg * COLSPW + tid;
    float rn = rnorm[nn];
    rnL[tid] = rn;
    di2sL[tid] = (rn * S[(size_t)nn * NDIM + nn]) * rn;
  }
  __syncthreads();
  if (tid < 64) {
    float v = di2sL[tid];
    int id = wg * COLSPW + tid;
#pragma unroll
    for (int m = 32; m >= 1; m >>= 1)
      vimerge(v, id, __shfl_xor(v, m, 64), __shfl_xor(id, m, 64));
    if (tid == 0) atomicMax(&gmax[0], packvi(v, id));
  }
  gbar(barcnt, 1 * NWG);

  for (int i = 0; i < TSTEPS; ++i) {
    // ---- winner of step i: single 8B load ----
    unsigned long long p = gmax[i];
    const int j = NDIM - 1 - (int)(p & 0xFFFFFFFFu);
    unsigned u = (unsigned)(p >> 32);
    u = (u & 0x80000000u) ? (u ^ 0x80000000u) : ~u;
    const float dj = __uint_as_float(u);
    if (wg == 0 && tid == 0) sel[i] = j;
    if (i == TSTEPS - 1) break;  // last step: selection only

    // ---- contraction s = sum_t cis[t][j] * cis[t][n] (zero tail exact) ----
    const float4* cjrow = (const float4*)(cisT + (size_t)j * TSTEPS);
    float rj = 0.f, kjS = 0.f;
    if (lane == 0) { rj = rnorm[j]; kjS = S[(size_t)j * NDIM + n]; }

    float s0 = 0.f, s1 = 0.f, s2 = 0.f, s3 = 0.f;
#pragma unroll
    for (int blk = 0; blk < 4; ++blk) {
      if (i > blk * 256) {  // uniform scalar guard; tail elements are zero
        const int q0 = blk * 64 + lane;
        float4 c0 = crow[q0];      float4 e0 = cjrow[q0];
        float4 c1 = crow[q0 + 16]; float4 e1 = cjrow[q0 + 16];
        float4 c2 = crow[q0 + 32]; float4 e2 = cjrow[q0 + 32];
        float4 c3 = crow[q0 + 48]; float4 e3 = cjrow[q0 + 48];
        s0 = fmaf(c0.x, e0.x, s0); s0 = fmaf(c0.y, e0.y, s0);
        s0 = fmaf(c0.z, e0.z, s0); s0 = fmaf(c0.w, e0.w, s0);
        s1 = fmaf(c1.x, e1.x, s1); s1 = fmaf(c1.y, e1.y, s1);
        s1 = fmaf(c1.z, e1.z, s1); s1 = fmaf(c1.w, e1.w, s1);
        s2 = fmaf(c2.x, e2.x, s2); s2 = fmaf(c2.y, e2.y, s2);
        s2 = fmaf(c2.z, e2.z, s2); s2 = fmaf(c2.w, e2.w, s2);
        s3 = fmaf(c3.x, e3.x, s3); s3 = fmaf(c3.y, e3.y, s3);
        s3 = fmaf(c3.z, e3.z, s3); s3 = fmaf(c3.w, e3.w, s3);
      }
    }
    float s = (s0 + s1) + (s2 + s3);
    s += __shfl_xor(s, 8, 64);
    s += __shfl_xor(s, 4, 64);
    s += __shfl_xor(s, 2, 64);
    s += __shfl_xor(s, 1, 64);

    if (lane == 0) {
      float kjn = (rj * kjS) * rnL[col];
      float eis = (kjn - s) / sqrtf(dj);
      float d = __fsub_rn(di2sL[col], __fmul_rn(eis, eis));
      if (n == j) d = -INFINITY;
      di2sL[col] = d;
      cisT[(size_t)n * TSTEPS + i] = eis;
    }
    __syncthreads();

    // ---- partial argmax for step i+1, folded into atomicMax ----
    if (tid < 64) {
      float v = di2sL[tid];
      int id = wg * COLSPW + tid;
#pragma unroll
      for (int m = 32; m >= 1; m >>= 1)
        vimerge(v, id, __shfl_xor(v, m, 64), __shfl_xor(id, m, 64));
      if (tid == 0) atomicMax(&gmax[i + 1], packvi(v, id));
    }
    gbar(barcnt, (unsigned)(i + 2) * NWG);
  }
}

extern "C" void kernel_launch(void* const* d_in, const int* in_sizes, int n_in,
                              void* d_out, int out_size, void* d_ws, size_t ws_size,
                              hipStream_t stream) {
  const float* X = (const float*)d_in[0];      // [2,4096,1024] f32
  const float* attn = (const float*)d_in[1];   // [2,4096] f32
  int* sel = (int*)d_out;                      // [1024] int32
  char* ws = (char*)d_ws;

  float* mm = (float*)ws;                                    // 8 B
  float* rnorm = (float*)(ws + 4096);                        // 16 KB
  unsigned long long* gmax = (unsigned long long*)(ws + 24576);  // 8 KB
  unsigned* barcnt = (unsigned*)(ws + 40960);                // 64 B
  char* big = ws + 65536;
  float* Xn = (float*)big;                                   // 16 MB
  float* S = (float*)(big + (size_t)16 * 1024 * 1024);       // 64 MB
  float* cisT = (float*)(big + (size_t)80 * 1024 * 1024);    // 16 MB

  const int nattn = in_sizes[1];  // 8192

  hipMemsetAsync(barcnt, 0, 64, stream);
  hipMemsetAsync(gmax, 0, TSTEPS * sizeof(unsigned long long), stream);
  hipMemsetAsync(cisT, 0, (size_t)NDIM * TSTEPS * sizeof(float), stream);
  k_minmax<<<1, 256, 0, stream>>>(attn, nattn, mm);
  k_prep<<<NDIM, 256, 0, stream>>>(X, attn, mm, Xn, rnorm);
  k_gemm<<<64 * 64, 256, 0, stream>>>(Xn, S);
  k_scan<<<NWG, NTHR, 0, stream>>>(S, rnorm, cisT, gmax, barcnt, sel);
}